// Round 10
// baseline (50.077 us; speedup 1.0000x reference)
//
#include <hip/hip_runtime.h>
#include <hip/hip_bf16.h>

#define NTOK 16384
#define DIM  2048
#define NE   64
#define TPB  64                 // tokens per block
#define CHK  128                // k per chunk (512 B per row)
#define NCH  (DIM / CHK)        // 16 chunks
#define RING 3
#define NKS_ALL (DIM / 32)      // 64 total k-steps

typedef __attribute__((ext_vector_type(8))) short  short8;
typedef __attribute__((ext_vector_type(4))) float  f32x4;

static __device__ __forceinline__ unsigned short f2bf(float f) {
    unsigned u = __float_as_uint(f);
    unsigned r = (u + 0x7fffu + ((u >> 16) & 1u)) >> 16;   // RNE
    return (unsigned short)r;
}
static __device__ __forceinline__ float bf2f(unsigned short h) {
    return __uint_as_float(((unsigned)h) << 16);
}
static __device__ __forceinline__ void cvt_pair(float x0, float x1,
                                                unsigned& hi, unsigned& lo) {
    union { __hip_bfloat162 b; unsigned u; } h, l;
    h.b = __float22bfloat162_rn(float2{x0, x1});           // v_cvt_pk_bf16_f32
    float h0 = __uint_as_float(h.u << 16);
    float h1 = __uint_as_float(h.u & 0xffff0000u);
    l.b = __float22bfloat162_rn(float2{x0 - h0, x1 - h1});
    hi = h.u; lo = l.u;
}

#define GLOAD_LDS(gp, lp) \
    __builtin_amdgcn_global_load_lds( \
        (const __attribute__((address_space(1))) unsigned int*)(const void*)(gp), \
        (__attribute__((address_space(3))) unsigned int*)(void*)(lp), 16, 0, 0)

// ---- prologue: split W into hi/lo bf16, packed in MFMA B-fragment order ----
__global__ void pack_w(const float* __restrict__ W,
                       unsigned short* __restrict__ WH,
                       unsigned short* __restrict__ WL) {
    int idx = blockIdx.x * 256 + threadIdx.x;
    if (idx >= DIM * NE) return;
    int k = idx / NE, e = idx % NE;
    float w = W[idx];
    unsigned short h = f2bf(w);
    unsigned short l = f2bf(w - bf2f(h));
    int etile = e >> 4, col = e & 15;
    int kstep = k >> 5, lsub = (k >> 3) & 3, j = k & 7;
    size_t off = (((size_t)etile * NKS_ALL + kstep) * 64 + (lsub * 16 + col)) * 8 + j;
    WH[off] = h;
    WL[off] = l;
}

// ---- main: full-K waves, contiguous X ring via global_load_lds, B in regs ----
__global__ __launch_bounds__(512, 2) void router_mfma(
    const float* __restrict__ X,
    const unsigned short* __restrict__ WH,
    const unsigned short* __restrict__ WL,
    const float* __restrict__ B, float* __restrict__ out)
{
    __shared__ __align__(16) float xbuf[RING][TPB][CHK];   // 96 KB X ring
    __shared__ float lg[TPB][65];                          // 16.6 KB logits

    const int tid  = threadIdx.x;
    const int lane = tid & 63;
    const int wv   = tid >> 6;                                  // 0..7
    const int tt   = __builtin_amdgcn_readfirstlane(wv & 3);    // token tile
    const int eh   = __builtin_amdgcn_readfirstlane(wv >> 2);   // expert half
    const int t0   = blockIdx.x * TPB;

    // staging: wave wv owns rows [wv*8, wv*8+8); each instr = 2 rows x 512 B contiguous
    const int sgr = lane & 31;          // granule 0..31 within a row

#define STAGE(c) do {                                                             \
    _Pragma("unroll")                                                             \
    for (int i_ = 0; i_ < 4; ++i_) {                                              \
        int row_ = wv * 8 + i_ * 2 + (lane >> 5);                                 \
        int grG_ = sgr ^ (row_ & 7);          /* src pre-swizzle, within 128 B */ \
        const float* g_ = X + (size_t)(t0 + row_) * DIM + (c) * CHK + grG_ * 4;   \
        GLOAD_LDS(g_, &xbuf[(c) % RING][wv * 8 + i_ * 2][0]);                     \
    }                                                                             \
  } while (0)

    f32x4 acc[2];
    acc[0] = (f32x4){0.f, 0.f, 0.f, 0.f};
    acc[1] = (f32x4){0.f, 0.f, 0.f, 0.f};

    const int g   = lane >> 4;      // k-quarter 0..3
    const int ar  = lane & 15;      // A row within tile / C col
    const int row = tt * 16 + ar;
    const int s7  = row & 7;

    STAGE(0);
    STAGE(1);
    asm volatile("s_waitcnt vmcnt(4)" ::: "memory");   // chunk 0 landed
    __builtin_amdgcn_s_barrier();
    __builtin_amdgcn_sched_barrier(0);

#pragma unroll 1
    for (int c = 0; c < NCH; ++c) {
        // ---- B-loads FIRST (oldest in queue; their waits leave stage in flight)
        short8 bh[4][2], bl[4][2];
#pragma unroll
        for (int ks = 0; ks < 4; ++ks)
#pragma unroll
            for (int et = 0; et < 2; ++et) {
                int etg = eh * 2 + et;
                size_t foff = (((size_t)etg * NKS_ALL + c * 4 + ks) * 64 + lane) * 8;
                bh[ks][et] = *(const short8*)(WH + foff);
                bl[ks][et] = *(const short8*)(WL + foff);
            }
        __builtin_amdgcn_sched_barrier(0);

        // ---- async-prefetch chunk c+2 (newest; stays outstanding through compute)
        if (c + 2 < NCH) STAGE(c + 2);
        __builtin_amdgcn_sched_barrier(0);

        // ---- compute on chunk c
        const float* xrow = &xbuf[c % RING][row][0];
#pragma unroll
        for (int ks = 0; ks < 4; ++ks) {
            int g0 = (ks * 8 + 2 * g) ^ s7;          // swizzled granule of 8-float A-frag
            int g1 = (ks * 8 + 2 * g + 1) ^ s7;
            float4 xa = *(const float4*)(xrow + g0 * 4);
            float4 xb = *(const float4*)(xrow + g1 * 4);

            union { unsigned u[4]; short8 s8; } ah, al;
            cvt_pair(xa.x, xa.y, ah.u[0], al.u[0]);
            cvt_pair(xa.z, xa.w, ah.u[1], al.u[1]);
            cvt_pair(xb.x, xb.y, ah.u[2], al.u[2]);
            cvt_pair(xb.z, xb.w, ah.u[3], al.u[3]);

#pragma unroll
            for (int et = 0; et < 2; ++et) {
                acc[et] = __builtin_amdgcn_mfma_f32_16x16x32_bf16(ah.s8, bh[ks][et], acc[et], 0, 0, 0);
                acc[et] = __builtin_amdgcn_mfma_f32_16x16x32_bf16(ah.s8, bl[ks][et], acc[et], 0, 0, 0);
                acc[et] = __builtin_amdgcn_mfma_f32_16x16x32_bf16(al.s8, bh[ks][et], acc[et], 0, 0, 0);
            }
        }
        __builtin_amdgcn_sched_barrier(0);
        __builtin_amdgcn_s_barrier();     // raw: no vmcnt drain (stage c+2 stays in flight)
        __builtin_amdgcn_sched_barrier(0);
    }

    // ---- epilogue: bias + logits to LDS (C-frag: col=lane&15, row=g*4+q) ----
#pragma unroll
    for (int et = 0; et < 2; ++et) {
        int etg = eh * 2 + et;
        float bias = B[etg * 16 + ar];
#pragma unroll
        for (int q = 0; q < 4; ++q)
            lg[tt * 16 + g * 4 + q][etg * 16 + ar] = acc[et][q] + bias;
    }
    __syncthreads();

    float* out_nv  = out + (size_t)NTOK * NE;
    float* out_idx = out_nv + (size_t)NTOK * 2;

#pragma unroll
    for (int k = 0; k < 2; ++k) {
        const int idx = tid + k * 512;          // 1024 quads = 64 tok x 16
        const int rt = idx >> 4;
        const int re = (idx & 15) * 4;
        float4 s;
        s.x = lg[rt][re + 0];
        s.y = lg[rt][re + 1];
        s.z = lg[rt][re + 2];
        s.w = lg[rt][re + 3];
        *(float4*)&out[(size_t)(t0 + rt) * NE + re] = s;
    }

    if (tid < 4 * TPB) {
        const int tk = tid >> 2;         // token 0..63
        const int q  = tid & 3;          // expert quarter
        float m1 = -1e30f, m2 = -1e30f;
        int   i1 = 0, i2 = 0;
#pragma unroll
        for (int j = 0; j < 16; ++j) {
            int   e = q * 16 + j;
            float v = lg[tk][e];
            if (v > m1)      { m2 = m1; i2 = i1; m1 = v; i1 = e; }
            else if (v > m2) { m2 = v;  i2 = e; }
        }
#pragma unroll
        for (int d = 1; d <= 2; d <<= 1) {
            float om1 = __shfl_xor(m1, d);
            int   oi1 = __shfl_xor(i1, d);
            float om2 = __shfl_xor(m2, d);
            int   oi2 = __shfl_xor(i2, d);
            bool agt = (m1 > om1) || (m1 == om1 && i1 < oi1);
            float a1 = agt ? m1 : om1;  int ai1 = agt ? i1 : oi1;
            float c2 = agt ? m2 : om2;  int ci2 = agt ? i2 : oi2;
            float c1 = agt ? om1 : m1;  int ci1 = agt ? oi1 : i1;
            bool sgt = (c2 > c1) || (c2 == c1 && ci2 < ci1);
            m1 = a1; i1 = ai1;
            m2 = sgt ? c2 : c1; i2 = sgt ? ci2 : ci1;
        }
        if (q == 0) {
            float e2  = expf(m2 - m1);
            float inv = 1.f / (1.f + e2);
            int t = t0 + tk;
            out_nv[t * 2 + 0]  = inv;
            out_nv[t * 2 + 1]  = e2 * inv;
            out_idx[t * 2 + 0] = (float)i1;
            out_idx[t * 2 + 1] = (float)i2;
        }
    }
}

extern "C" void kernel_launch(void* const* d_in, const int* in_sizes, int n_in,
                              void* d_out, int out_size, void* d_ws, size_t ws_size,
                              hipStream_t stream) {
    const float* X = (const float*)d_in[0];
    const float* W = (const float*)d_in[1];
    const float* B = (const float*)d_in[2];
    float* out = (float*)d_out;

    unsigned short* WH = (unsigned short*)d_ws;          // 256 KB
    unsigned short* WL = WH + (size_t)DIM * NE;          // +256 KB

    hipLaunchKernelGGL(pack_w, dim3((DIM * NE + 255) / 256), dim3(256), 0, stream, W, WH, WL);
    hipLaunchKernelGGL(router_mfma, dim3(NTOK / TPB), dim3(512), 0, stream, X, WH, WL, B, out);
}

// Round 11
// 46.697 us; speedup vs baseline: 1.0724x; 1.0724x over previous
//
#include <hip/hip_runtime.h>
#include <hip/hip_bf16.h>

#define NTOK 16384
#define DIM  2048
#define NE   64
#define TPB  64                 // tokens per block
#define CHK  128                // k-floats per chunk (512 B per row)
#define NCH  (DIM / CHK)        // 16 chunks
#define PITCH 132               // LDS row pitch in floats (528 B): 16B-aligned, 8-way max on b128
#define NKS_ALL (DIM / 32)      // 64 total k-steps
#define CK(x) ((x) < NCH ? (x) : 0)

typedef __attribute__((ext_vector_type(8))) short  short8;
typedef __attribute__((ext_vector_type(4))) float  f32x4;

static __device__ __forceinline__ unsigned short f2bf(float f) {
    unsigned u = __float_as_uint(f);
    unsigned r = (u + 0x7fffu + ((u >> 16) & 1u)) >> 16;   // RNE
    return (unsigned short)r;
}
static __device__ __forceinline__ float bf2f(unsigned short h) {
    return __uint_as_float(((unsigned)h) << 16);
}
static __device__ __forceinline__ void cvt_pair(float x0, float x1,
                                                unsigned& hi, unsigned& lo) {
    union { __hip_bfloat162 b; unsigned u; } h, l;
    h.b = __float22bfloat162_rn(float2{x0, x1});           // v_cvt_pk_bf16_f32
    float h0 = __uint_as_float(h.u << 16);
    float h1 = __uint_as_float(h.u & 0xffff0000u);
    l.b = __float22bfloat162_rn(float2{x0 - h0, x1 - h1});
    hi = h.u; lo = l.u;
}

#define GLOAD_LDS(gp, lp) \
    __builtin_amdgcn_global_load_lds( \
        (const __attribute__((address_space(1))) unsigned int*)(const void*)(gp), \
        (__attribute__((address_space(3))) unsigned int*)(void*)(lp), 16, 0, 0)

// ---- prologue: split W into hi/lo bf16, packed in MFMA B-fragment order ----
__global__ void pack_w(const float* __restrict__ W,
                       unsigned short* __restrict__ WH,
                       unsigned short* __restrict__ WL) {
    int idx = blockIdx.x * 256 + threadIdx.x;
    if (idx >= DIM * NE) return;
    int k = idx / NE, e = idx % NE;
    float w = W[idx];
    unsigned short h = f2bf(w);
    unsigned short l = f2bf(w - bf2f(h));
    int etile = e >> 4, col = e & 15;
    int kstep = k >> 5, lsub = (k >> 3) & 3, j = k & 7;
    size_t off = (((size_t)etile * NKS_ALL + kstep) * 64 + (lsub * 16 + col)) * 8 + j;
    WH[off] = h;
    WL[off] = l;
}

// ---- main: monotone 512B-run X staging, ring-4, counted vmcnt, B dbuf regs ----
__global__ __launch_bounds__(512, 2) void router_mfma(
    const float* __restrict__ X,
    const unsigned short* __restrict__ WH,
    const unsigned short* __restrict__ WL,
    const float* __restrict__ B, float* __restrict__ out)
{
    __shared__ __align__(16) float xbuf[4][TPB][PITCH];    // 135.2 KB X ring
    __shared__ float lg[TPB][65];                          // 16.6 KB logits

    const int tid  = threadIdx.x;
    const int lane = tid & 63;
    const int wv   = tid >> 6;                                  // 0..7
    const int tt   = __builtin_amdgcn_readfirstlane(wv & 3);    // token tile
    const int eh   = __builtin_amdgcn_readfirstlane(wv >> 2);   // expert half
    const int t0   = blockIdx.x * TPB;

    // one instr = one row's 512 B chunk, monotone contiguous (lanes 0..31 x 16 B)
#define STAGE(cs, slot) do {                                                      \
    if (lane < 32) {                                                              \
        _Pragma("unroll")                                                         \
        for (int i_ = 0; i_ < 8; ++i_) {                                          \
            int row_ = wv * 8 + i_;                                               \
            const float* g_ = X + (size_t)(t0 + row_) * DIM + (cs) * CHK + lane * 4; \
            GLOAD_LDS(g_, &xbuf[slot][row_][0]);                                  \
        }                                                                         \
    }                                                                             \
  } while (0)

#define LOADB(bh_, bl_, c) do {                                                   \
    _Pragma("unroll")                                                             \
    for (int ks_ = 0; ks_ < 4; ++ks_) {                                           \
        _Pragma("unroll")                                                         \
        for (int et_ = 0; et_ < 2; ++et_) {                                       \
            int etg_ = eh * 2 + et_;                                              \
            size_t foff_ = (((size_t)etg_ * NKS_ALL + (c) * 4 + ks_) * 64 + lane) * 8; \
            bh_[ks_][et_] = *(const short8*)(WH + foff_);                         \
            bl_[ks_][et_] = *(const short8*)(WL + foff_);                         \
        }                                                                         \
    }                                                                             \
  } while (0)

#define COMPUTE(slot, bh_, bl_) do {                                              \
    _Pragma("unroll")                                                             \
    for (int ks_ = 0; ks_ < 4; ++ks_) {                                           \
        const float* xr_ = &xbuf[slot][row][ks_ * 32 + g * 8];                    \
        float4 xa_ = *(const float4*)xr_;                                         \
        float4 xb_ = *(const float4*)(xr_ + 4);                                   \
        union { unsigned u[4]; short8 s8; } ah_, al_;                             \
        cvt_pair(xa_.x, xa_.y, ah_.u[0], al_.u[0]);                               \
        cvt_pair(xa_.z, xa_.w, ah_.u[1], al_.u[1]);                               \
        cvt_pair(xb_.x, xb_.y, ah_.u[2], al_.u[2]);                               \
        cvt_pair(xb_.z, xb_.w, ah_.u[3], al_.u[3]);                               \
        _Pragma("unroll")                                                         \
        for (int et_ = 0; et_ < 2; ++et_) {                                       \
            acc[et_] = __builtin_amdgcn_mfma_f32_16x16x32_bf16(ah_.s8, bh_[ks_][et_], acc[et_], 0, 0, 0); \
            acc[et_] = __builtin_amdgcn_mfma_f32_16x16x32_bf16(ah_.s8, bl_[ks_][et_], acc[et_], 0, 0, 0); \
            acc[et_] = __builtin_amdgcn_mfma_f32_16x16x32_bf16(al_.s8, bh_[ks_][et_], acc[et_], 0, 0, 0); \
        }                                                                         \
    }                                                                             \
  } while (0)

#define SYNCPT() do {                                                             \
    asm volatile("s_waitcnt vmcnt(32)" ::: "memory");                             \
    __builtin_amdgcn_sched_barrier(0);                                            \
    __builtin_amdgcn_s_barrier();                                                 \
    __builtin_amdgcn_sched_barrier(0);                                            \
  } while (0)

    f32x4 acc[2];
    acc[0] = (f32x4){0.f, 0.f, 0.f, 0.f};
    acc[1] = (f32x4){0.f, 0.f, 0.f, 0.f};

    const int g   = lane >> 4;          // k-quarter within 32-step
    const int ar  = lane & 15;          // A row within tile / C col
    const int row = tt * 16 + ar;

    short8 bhA[4][2], blA[4][2], bhB[4][2], blB[4][2];

    // prologue: establish steady-state queue [stage0, B0, stage1]
    STAGE(0, 0);
    LOADB(bhA, blA, 0);
    STAGE(1, 1);

#pragma unroll 1
    for (int i = 0; i < NCH / 2; ++i) {
        const int c0 = 2 * i, c1 = 2 * i + 1;

        LOADB(bhB, blB, c0 + 1);              // c0+1 <= 15 always
        STAGE(CK(c0 + 2), (c0 + 2) & 3);
        SYNCPT();                             // retire stage(c0)+B(c0); chunk c0 visible block-wide
        COMPUTE((c0) & 3, bhA, blA);

        LOADB(bhA, blA, CK(c1 + 1));          // dead at i=7 (harmless)
        STAGE(CK(c1 + 2), (c1 + 2) & 3);
        SYNCPT();
        COMPUTE((c1) & 3, bhB, blB);
    }

    // ---- epilogue: bias + logits to LDS (C-frag: col=lane&15, row=g*4+q) ----
#pragma unroll
    for (int et = 0; et < 2; ++et) {
        int etg = eh * 2 + et;
        float bias = B[etg * 16 + ar];
#pragma unroll
        for (int q = 0; q < 4; ++q)
            lg[tt * 16 + g * 4 + q][etg * 16 + ar] = acc[et][q] + bias;
    }
    __syncthreads();

    float* out_nv  = out + (size_t)NTOK * NE;
    float* out_idx = out_nv + (size_t)NTOK * 2;

#pragma unroll
    for (int k = 0; k < 2; ++k) {
        const int idx = tid + k * 512;          // 1024 quads = 64 tok x 16
        const int rt = idx >> 4;
        const int re = (idx & 15) * 4;
        float4 s;
        s.x = lg[rt][re + 0];
        s.y = lg[rt][re + 1];
        s.z = lg[rt][re + 2];
        s.w = lg[rt][re + 3];
        *(float4*)&out[(size_t)(t0 + rt) * NE + re] = s;
    }

    if (tid < 4 * TPB) {
        const int tk = tid >> 2;         // token 0..63
        const int q  = tid & 3;          // expert quarter
        float m1 = -1e30f, m2 = -1e30f;
        int   i1 = 0, i2 = 0;
#pragma unroll
        for (int j = 0; j < 16; ++j) {
            int   e = q * 16 + j;
            float v = lg[tk][e];
            if (v > m1)      { m2 = m1; i2 = i1; m1 = v; i1 = e; }
            else if (v > m2) { m2 = v;  i2 = e; }
        }
#pragma unroll
        for (int d = 1; d <= 2; d <<= 1) {
            float om1 = __shfl_xor(m1, d);
            int   oi1 = __shfl_xor(i1, d);
            float om2 = __shfl_xor(m2, d);
            int   oi2 = __shfl_xor(i2, d);
            bool agt = (m1 > om1) || (m1 == om1 && i1 < oi1);
            float a1 = agt ? m1 : om1;  int ai1 = agt ? i1 : oi1;
            float c2 = agt ? m2 : om2;  int ci2 = agt ? i2 : oi2;
            float c1 = agt ? om1 : m1;  int ci1 = agt ? oi1 : i1;
            bool sgt = (c2 > c1) || (c2 == c1 && ci2 < ci1);
            m1 = a1; i1 = ai1;
            m2 = sgt ? c2 : c1; i2 = sgt ? ci2 : ci1;
        }
        if (q == 0) {
            float e2  = expf(m2 - m1);
            float inv = 1.f / (1.f + e2);
            int t = t0 + tk;
            out_nv[t * 2 + 0]  = inv;
            out_nv[t * 2 + 1]  = e2 * inv;
            out_idx[t * 2 + 0] = (float)i1;
            out_idx[t * 2 + 1] = (float)i2;
        }
    }
}

extern "C" void kernel_launch(void* const* d_in, const int* in_sizes, int n_in,
                              void* d_out, int out_size, void* d_ws, size_t ws_size,
                              hipStream_t stream) {
    const float* X = (const float*)d_in[0];
    const float* W = (const float*)d_in[1];
    const float* B = (const float*)d_in[2];
    float* out = (float*)d_out;

    unsigned short* WH = (unsigned short*)d_ws;          // 256 KB
    unsigned short* WL = WH + (size_t)DIM * NE;          // +256 KB

    hipLaunchKernelGGL(pack_w, dim3((DIM * NE + 255) / 256), dim3(256), 0, stream, W, WH, WL);
    hipLaunchKernelGGL(router_mfma, dim3(NTOK / TPB), dim3(512), 0, stream, X, WH, WL, B, out);
}

// Round 12
// 45.659 us; speedup vs baseline: 1.0968x; 1.0227x over previous
//
#include <hip/hip_runtime.h>
#include <hip/hip_bf16.h>

#define NTOK 16384
#define DIM  2048
#define NE   64
#define TPB  64                 // tokens per block
#define CHK  128                // k-floats per chunk (512 B per row, 32 KB/chunk)
#define NCH  (DIM / CHK)        // 16 chunks
#define NKS_ALL (DIM / 32)      // 64 total k-steps

typedef __attribute__((ext_vector_type(8))) short  short8;
typedef __attribute__((ext_vector_type(4))) float  f32x4;

static __device__ __forceinline__ unsigned short f2bf(float f) {
    unsigned u = __float_as_uint(f);
    unsigned r = (u + 0x7fffu + ((u >> 16) & 1u)) >> 16;   // RNE
    return (unsigned short)r;
}
static __device__ __forceinline__ float bf2f(unsigned short h) {
    return __uint_as_float(((unsigned)h) << 16);
}
static __device__ __forceinline__ void cvt_pair(float x0, float x1,
                                                unsigned& hi, unsigned& lo) {
    union { __hip_bfloat162 b; unsigned u; } h, l;
    h.b = __float22bfloat162_rn(float2{x0, x1});           // v_cvt_pk_bf16_f32
    float h0 = __uint_as_float(h.u << 16);
    float h1 = __uint_as_float(h.u & 0xffff0000u);
    l.b = __float22bfloat162_rn(float2{x0 - h0, x1 - h1});
    hi = h.u; lo = l.u;
}

#define GLOAD_LDS(gp, lp) \
    __builtin_amdgcn_global_load_lds( \
        (const __attribute__((address_space(1))) unsigned int*)(const void*)(gp), \
        (__attribute__((address_space(3))) unsigned int*)(void*)(lp), 16, 0, 0)

// ---- prologue: split W into hi/lo bf16, packed in MFMA B-fragment order ----
__global__ void pack_w(const float* __restrict__ W,
                       unsigned short* __restrict__ WH,
                       unsigned short* __restrict__ WL) {
    int idx = blockIdx.x * 256 + threadIdx.x;
    if (idx >= DIM * NE) return;
    int k = idx / NE, e = idx % NE;
    float w = W[idx];
    unsigned short h = f2bf(w);
    unsigned short l = f2bf(w - bf2f(h));
    int etile = e >> 4, col = e & 15;
    int kstep = k >> 5, lsub = (k >> 3) & 3, j = k & 7;
    size_t off = (((size_t)etile * NKS_ALL + kstep) * 64 + (lsub * 16 + col)) * 8 + j;
    WH[off] = h;
    WL[off] = l;
}

// ---- main: async X ring (counted vmcnt), B-minimal kg-split, reg B dbuf ----
__global__ __launch_bounds__(512, 2) void router_mfma(
    const float* __restrict__ X,
    const unsigned short* __restrict__ WH,
    const unsigned short* __restrict__ WL,
    const float* __restrict__ B, float* __restrict__ out)
{
    // 64 KB: ring of 2 x [64 rows][512 B] during loop; red[4][64][64] after
    __shared__ __align__(16) unsigned char smem[65536];

    const int tid  = threadIdx.x;
    const int lane = tid & 63;
    const int wv   = tid >> 6;                                  // 0..7
    const int ksl  = __builtin_amdgcn_readfirstlane(wv & 3);    // k-slot in chunk
    const int eh   = __builtin_amdgcn_readfirstlane(wv >> 2);   // expert half
    const int t0   = blockIdx.x * TPB;

    const int g  = lane >> 4;       // k-quarter within 32-step
    const int ar = lane & 15;       // A row within tile / C col
    const int s7 = ar & 7;          // row swizzle key (row&7 == ar&7)

    // full-wave stage: 1 instr = 2 rows x 512 B; source granule-XOR within 128 B
#define STAGE(c, slot) do {                                                       \
    _Pragma("unroll")                                                             \
    for (int i_ = 0; i_ < 4; ++i_) {                                              \
        int row_ = wv * 8 + i_ * 2 + (lane >> 5);                                 \
        int ln_  = lane & 31;                                                     \
        int sg_  = (ln_ & 24) | ((ln_ & 7) ^ (row_ & 7));                         \
        const float* g_ = X + (size_t)(t0 + row_) * DIM + (c) * CHK + sg_ * 4;    \
        GLOAD_LDS(g_, smem + (slot) * 32768 + (wv * 8 + i_ * 2) * 512);           \
    }                                                                             \
  } while (0)

#define LOADB(bh_, bl_, c) do {                                                   \
    _Pragma("unroll")                                                             \
    for (int et_ = 0; et_ < 2; ++et_) {                                           \
        int etg_ = eh * 2 + et_;                                                  \
        size_t foff_ = (((size_t)etg_ * NKS_ALL + (c) * 4 + ksl) * 64 + lane) * 8;\
        bh_[et_] = *(const short8*)(WH + foff_);                                  \
        bl_[et_] = *(const short8*)(WL + foff_);                                  \
    }                                                                             \
  } while (0)

#define COMPUTE(slot, bh_, bl_) do {                                              \
    const float* sb_ = (const float*)(smem + (slot) * 32768);                     \
    _Pragma("unroll")                                                             \
    for (int tt_ = 0; tt_ < 4; ++tt_) {                                           \
        int row_ = tt_ * 16 + ar;                                                 \
        int g0_  = ksl * 8 + g * 2;                                               \
        int p0_  = (g0_ & 24) | ((g0_ & 7) ^ s7);                                 \
        const float* xr_ = sb_ + row_ * 128;                                      \
        float4 xa_ = *(const float4*)(xr_ + p0_ * 4);                             \
        float4 xb_ = *(const float4*)(xr_ + (p0_ ^ 1) * 4);                       \
        union { unsigned u[4]; short8 s8; } ah_, al_;                             \
        cvt_pair(xa_.x, xa_.y, ah_.u[0], al_.u[0]);                               \
        cvt_pair(xa_.z, xa_.w, ah_.u[1], al_.u[1]);                               \
        cvt_pair(xb_.x, xb_.y, ah_.u[2], al_.u[2]);                               \
        cvt_pair(xb_.z, xb_.w, ah_.u[3], al_.u[3]);                               \
        _Pragma("unroll")                                                         \
        for (int et_ = 0; et_ < 2; ++et_) {                                       \
            acc[tt_][et_] = __builtin_amdgcn_mfma_f32_16x16x32_bf16(ah_.s8, bh_[et_], acc[tt_][et_], 0, 0, 0); \
            acc[tt_][et_] = __builtin_amdgcn_mfma_f32_16x16x32_bf16(ah_.s8, bl_[et_], acc[tt_][et_], 0, 0, 0); \
            acc[tt_][et_] = __builtin_amdgcn_mfma_f32_16x16x32_bf16(al_.s8, bh_[et_], acc[tt_][et_], 0, 0, 0); \
        }                                                                         \
    }                                                                             \
  } while (0)

#define SYNCPT() do {                                                             \
    __builtin_amdgcn_sched_barrier(0);                                            \
    asm volatile("s_waitcnt vmcnt(4)" ::: "memory");                              \
    __builtin_amdgcn_sched_barrier(0);                                            \
    __builtin_amdgcn_s_barrier();                                                 \
    __builtin_amdgcn_sched_barrier(0);                                            \
  } while (0)

    f32x4 acc[4][2];
#pragma unroll
    for (int t = 0; t < 4; ++t) {
        acc[t][0] = (f32x4){0.f, 0.f, 0.f, 0.f};
        acc[t][1] = (f32x4){0.f, 0.f, 0.f, 0.f};
    }

    short8 bhA[2], blA[2], bhB[2], blB[2];

    // prologue: queue = [stage0(4), B0(4), stage1(4)]; retire st0+B0, keep st1
    STAGE(0, 0);
    LOADB(bhA, blA, 0);
    STAGE(1, 1);
    SYNCPT();

#pragma unroll 1
    for (int i = 0; i < NCH / 2; ++i) {
        const int c0 = 2 * i, c1 = 2 * i + 1;

        LOADB(bhB, blB, c0 + 1);                    // c0+1 <= 15
        __builtin_amdgcn_sched_barrier(0);
        COMPUTE(c0 & 1, bhA, blA);                  // B(c0) already retired
        SYNCPT();                                   // retire stage(c0+1)
        if (c0 + 2 < NCH) STAGE(c0 + 2, c0 & 1);
        __builtin_amdgcn_sched_barrier(0);

        if (c1 + 1 < NCH) LOADB(bhA, blA, c1 + 1);
        __builtin_amdgcn_sched_barrier(0);
        COMPUTE(c1 & 1, bhB, blB);                  // compiler counts vmcnt for B(c1)
        SYNCPT();
        if (c1 + 2 < NCH) STAGE(c1 + 2, c1 & 1);
        __builtin_amdgcn_sched_barrier(0);
    }

    // ---- epilogue: ring is dead; alias red[4][64][64] over smem ----
    __syncthreads();
    float* red = (float*)smem;                      // red[ksl][row][col], 64 KB

#pragma unroll
    for (int tt = 0; tt < 4; ++tt)
#pragma unroll
        for (int et = 0; et < 2; ++et) {
            int col = (eh * 2 + et) * 16 + ar;
#pragma unroll
            for (int q = 0; q < 4; ++q)
                red[(ksl * 64 + tt * 16 + g * 4 + q) * 64 + col] = acc[tt][et][q];
        }
    __syncthreads();

    float* out_nv  = out + (size_t)NTOK * NE;
    float* out_idx = out_nv + (size_t)NTOK * 2;

    // reduce over 4 ksl, add bias, store logits; winners back into red[0] region
#pragma unroll
    for (int k = 0; k < 2; ++k) {
        const int idx = tid + k * 512;              // 1024 quads = 64 tok x 16
        const int rt = idx >> 4;
        const int re = (idx & 15) * 4;
        float4 s = {0.f, 0.f, 0.f, 0.f};
#pragma unroll
        for (int gk = 0; gk < 4; ++gk) {
            const float* p = red + (gk * 64 + rt) * 64 + re;
            s.x += p[0]; s.y += p[1]; s.z += p[2]; s.w += p[3];
        }
        float4 bb = *(const float4*)(B + re);
        s.x += bb.x; s.y += bb.y; s.z += bb.z; s.w += bb.w;
        *(float4*)&out[(size_t)(t0 + rt) * NE + re] = s;
        float* q = red + rt * 64 + re;              // red[0] region, slot owned
        q[0] = s.x; q[1] = s.y; q[2] = s.z; q[3] = s.w;
    }
    __syncthreads();

    // top-2 + renormalize: 4 lanes/token, shfl-merge (lowest-index ties)
    if (tid < 4 * TPB) {
        const int tk = tid >> 2;
        const int q  = tid & 3;
        float m1 = -1e30f, m2 = -1e30f;
        int   i1 = 0, i2 = 0;
#pragma unroll
        for (int j = 0; j < 16; ++j) {
            int   e = q * 16 + j;
            float v = red[tk * 64 + e];
            if (v > m1)      { m2 = m1; i2 = i1; m1 = v; i1 = e; }
            else if (v > m2) { m2 = v;  i2 = e; }
        }
#pragma unroll
        for (int d = 1; d <= 2; d <<= 1) {
            float om1 = __shfl_xor(m1, d);
            int   oi1 = __shfl_xor(i1, d);
            float om2 = __shfl_xor(m2, d);
            int   oi2 = __shfl_xor(i2, d);
            bool agt = (m1 > om1) || (m1 == om1 && i1 < oi1);
            float a1 = agt ? m1 : om1;  int ai1 = agt ? i1 : oi1;
            float c2 = agt ? m2 : om2;  int ci2 = agt ? i2 : oi2;
            float c1 = agt ? om1 : m1;  int ci1 = agt ? oi1 : i1;
            bool sgt = (c2 > c1) || (c2 == c1 && ci2 < ci1);
            m1 = a1; i1 = ai1;
            m2 = sgt ? c2 : c1; i2 = sgt ? ci2 : ci1;
        }
        if (q == 0) {
            float e2  = expf(m2 - m1);
            float inv = 1.f / (1.f + e2);
            int t = t0 + tk;
            out_nv[t * 2 + 0]  = inv;
            out_nv[t * 2 + 1]  = e2 * inv;
            out_idx[t * 2 + 0] = (float)i1;
            out_idx[t * 2 + 1] = (float)i2;
        }
    }
}

extern "C" void kernel_launch(void* const* d_in, const int* in_sizes, int n_in,
                              void* d_out, int out_size, void* d_ws, size_t ws_size,
                              hipStream_t stream) {
    const float* X = (const float*)d_in[0];
    const float* W = (const float*)d_in[1];
    const float* B = (const float*)d_in[2];
    float* out = (float*)d_out;

    unsigned short* WH = (unsigned short*)d_ws;          // 256 KB
    unsigned short* WL = WH + (size_t)DIM * NE;          // +256 KB

    hipLaunchKernelGGL(pack_w, dim3((DIM * NE + 255) / 256), dim3(256), 0, stream, W, WH, WL);
    hipLaunchKernelGGL(router_mfma, dim3(NTOK / TPB), dim3(512), 0, stream, X, WH, WL, B, out);
}

// Round 13
// 36.658 us; speedup vs baseline: 1.3661x; 1.2455x over previous
//
#include <hip/hip_runtime.h>
#include <hip/hip_bf16.h>

#define NTOK 16384
#define DIM  2048
#define NE   64
#define TPB  64                // tokens per block = 4 tiles
#define NTILE 4
#define KG   8                 // wave = k-group
#define KPW  (DIM / KG)        // 256 k per wave
#define KSTEPS (KPW / 32)      // 8 mfma k-steps per wave
#define NKS_ALL (DIM / 32)     // 64 total k-steps
#define LP   65

typedef __attribute__((ext_vector_type(8))) short  short8;   // 8 bf16 (4 VGPRs)
typedef __attribute__((ext_vector_type(4))) float  f32x4;

static __device__ __forceinline__ unsigned short f2bf(float f) {
    unsigned u = __float_as_uint(f);
    unsigned r = (u + 0x7fffu + ((u >> 16) & 1u)) >> 16;   // RNE
    return (unsigned short)r;
}
static __device__ __forceinline__ float bf2f(unsigned short h) {
    return __uint_as_float(((unsigned)h) << 16);
}

// packed split: (x0,x1) -> hi word [bf(x1)|bf(x0)], lo word [bf(r1)|bf(r0)]
static __device__ __forceinline__ void cvt_pair(float x0, float x1,
                                                unsigned& hi, unsigned& lo) {
    union { __hip_bfloat162 b; unsigned u; } h, l;
    h.b = __float22bfloat162_rn(float2{x0, x1});           // v_cvt_pk_bf16_f32
    float h0 = __uint_as_float(h.u << 16);
    float h1 = __uint_as_float(h.u & 0xffff0000u);
    l.b = __float22bfloat162_rn(float2{x0 - h0, x1 - h1});
    hi = h.u; lo = l.u;
}

// ---- prologue: split W into hi/lo bf16, packed in MFMA B-fragment order ----
__global__ void pack_w(const float* __restrict__ W,
                       unsigned short* __restrict__ WH,
                       unsigned short* __restrict__ WL) {
    int idx = blockIdx.x * 256 + threadIdx.x;
    if (idx >= DIM * NE) return;
    int k = idx / NE, e = idx % NE;
    float w = W[idx];
    unsigned short h = f2bf(w);
    unsigned short l = f2bf(w - bf2f(h));
    int etile = e >> 4, col = e & 15;
    int kstep = k >> 5, lsub = (k >> 3) & 3, j = k & 7;
    size_t off = (((size_t)etile * NKS_ALL + kstep) * 64 + (lsub * 16 + col)) * 8 + j;
    WH[off] = h;
    WL[off] = l;
}

// ---- main: 3-pass split-bf16 MFMA; 8 waves, NTILE=4, depth-3 X prefetch ----
__global__ __launch_bounds__(512, 2) void router_mfma(
    const float* __restrict__ X,
    const unsigned short* __restrict__ WH,
    const unsigned short* __restrict__ WL,
    const float* __restrict__ B, float* __restrict__ out)
{
    __shared__ float red[KG][TPB][LP];   // 133 KB k-partials (lg folded into red[0])

    const int tid  = threadIdx.x;
    const int lane = tid & 63;
    const int kg   = __builtin_amdgcn_readfirstlane(tid >> 6);  // wave = k group 0..7
    const int t0   = blockIdx.x * TPB;

    const int arow = lane & 15;          // A row within 16-tile
    const int koff = (lane >> 4) * 8;    // k offset within 32-step

    const float* xp0 = X + (size_t)(t0 +  0 + arow) * DIM + kg * KPW + koff;
    const float* xp1 = X + (size_t)(t0 + 16 + arow) * DIM + kg * KPW + koff;
    const float* xp2 = X + (size_t)(t0 + 32 + arow) * DIM + kg * KPW + koff;
    const float* xp3 = X + (size_t)(t0 + 48 + arow) * DIM + kg * KPW + koff;

    const int ksbase = kg * KSTEPS;

    f32x4 acc[NTILE][4];
#pragma unroll
    for (int t = 0; t < NTILE; ++t)
#pragma unroll
        for (int et = 0; et < 4; ++et) acc[t][et] = (f32x4){0.f, 0.f, 0.f, 0.f};

    float4 xA[NTILE][2], xB[NTILE][2], xC[NTILE][2];
    short8 bhA[4], blA[4], bhB[4], blB[4];

#define LOADX(buf, s) do {                                                    \
    buf[0][0] = *(const float4*)(xp0 + (s) * 32);                             \
    buf[0][1] = *(const float4*)(xp0 + (s) * 32 + 4);                         \
    buf[1][0] = *(const float4*)(xp1 + (s) * 32);                             \
    buf[1][1] = *(const float4*)(xp1 + (s) * 32 + 4);                         \
    buf[2][0] = *(const float4*)(xp2 + (s) * 32);                             \
    buf[2][1] = *(const float4*)(xp2 + (s) * 32 + 4);                         \
    buf[3][0] = *(const float4*)(xp3 + (s) * 32);                             \
    buf[3][1] = *(const float4*)(xp3 + (s) * 32 + 4);                         \
  } while (0)

#define LOADB(bh_, bl_, s) do {                                               \
    _Pragma("unroll")                                                         \
    for (int et = 0; et < 4; ++et) {                                          \
        size_t foff = (((size_t)et * NKS_ALL + ksbase + (s)) * 64 + lane) * 8;\
        bh_[et] = *(const short8*)(WH + foff);                                \
        bl_[et] = *(const short8*)(WL + foff);                                \
    }                                                                         \
  } while (0)

#define COMPUTE(xv, bh_, bl_) do {                                            \
    _Pragma("unroll")                                                         \
    for (int t = 0; t < NTILE; ++t) {                                         \
        union { unsigned u[4]; short8 s8; } ah, al;                           \
        cvt_pair(xv[t][0].x, xv[t][0].y, ah.u[0], al.u[0]);                   \
        cvt_pair(xv[t][0].z, xv[t][0].w, ah.u[1], al.u[1]);                   \
        cvt_pair(xv[t][1].x, xv[t][1].y, ah.u[2], al.u[2]);                   \
        cvt_pair(xv[t][1].z, xv[t][1].w, ah.u[3], al.u[3]);                   \
        _Pragma("unroll")                                                     \
        for (int et = 0; et < 4; ++et) {                                      \
            acc[t][et] = __builtin_amdgcn_mfma_f32_16x16x32_bf16(ah.s8, bh_[et], acc[t][et], 0, 0, 0); \
            acc[t][et] = __builtin_amdgcn_mfma_f32_16x16x32_bf16(ah.s8, bl_[et], acc[t][et], 0, 0, 0); \
            acc[t][et] = __builtin_amdgcn_mfma_f32_16x16x32_bf16(al.s8, bh_[et], acc[t][et], 0, 0, 0); \
        }                                                                     \
    }                                                                         \
  } while (0)

    // prologue: X 3 steps deep, B 2 steps deep
    LOADX(xA, 0); LOADB(bhA, blA, 0);
    LOADX(xB, 1); LOADB(bhB, blB, 1);
    LOADX(xC, 2);

    // steady state: compute(s) then issue X(s+3), B(s+2) into freed buffers
    COMPUTE(xA, bhA, blA); LOADX(xA, 3); LOADB(bhA, blA, 2);
    COMPUTE(xB, bhB, blB); LOADX(xB, 4); LOADB(bhB, blB, 3);
    COMPUTE(xC, bhA, blA); LOADX(xC, 5); LOADB(bhA, blA, 4);
    COMPUTE(xA, bhB, blB); LOADX(xA, 6); LOADB(bhB, blB, 5);
    COMPUTE(xB, bhA, blA); LOADX(xB, 7); LOADB(bhA, blA, 6);
    COMPUTE(xC, bhB, blB);               LOADB(bhB, blB, 7);
    COMPUTE(xA, bhA, blA);
    COMPUTE(xB, bhB, blB);

    // C frag: col = lane&15, row = (lane>>4)*4 + r
#pragma unroll
    for (int t = 0; t < NTILE; ++t)
#pragma unroll
        for (int et = 0; et < 4; ++et)
#pragma unroll
            for (int r = 0; r < 4; ++r)
                red[kg][t * 16 + (lane >> 4) * 4 + r][et * 16 + (lane & 15)] = acc[t][et][r];
    __syncthreads();

    float* out_nv  = out + (size_t)NTOK * NE;
    float* out_idx = out_nv + (size_t)NTOK * 2;

    // ---- reduce over KG, add bias, store logits; winners back into red[0] ----
#pragma unroll
    for (int k = 0; k < 2; ++k) {
        const int idx = tid + k * 512;    // 1024 items: 64 tok x 16 col-quads
        const int rt = idx >> 4;
        const int re = (idx & 15) * 4;
        float4 s = {0.f, 0.f, 0.f, 0.f};
#pragma unroll
        for (int g = 0; g < KG; ++g) {
            s.x += red[g][rt][re + 0];
            s.y += red[g][rt][re + 1];
            s.z += red[g][rt][re + 2];
            s.w += red[g][rt][re + 3];
        }
        float4 bb = *(const float4*)(B + re);
        s.x += bb.x; s.y += bb.y; s.z += bb.z; s.w += bb.w;
        *(float4*)&out[(size_t)(t0 + rt) * NE + re] = s;
        red[0][rt][re + 0] = s.x;     // each slot owned by exactly this thread
        red[0][rt][re + 1] = s.y;
        red[0][rt][re + 2] = s.z;
        red[0][rt][re + 3] = s.w;
    }
    __syncthreads();

    // ---- top-2 + renormalize: 4 lanes/token, shfl-merge (lowest-index ties) ----
    if (tid < 4 * TPB) {
        const int tt = tid >> 2;         // token 0..63
        const int q  = tid & 3;          // expert quarter
        float m1 = -1e30f, m2 = -1e30f;
        int   i1 = 0, i2 = 0;
#pragma unroll
        for (int j = 0; j < 16; ++j) {
            int   e = q * 16 + j;
            float v = red[0][tt][e];
            if (v > m1)      { m2 = m1; i2 = i1; m1 = v; i1 = e; }
            else if (v > m2) { m2 = v;  i2 = e; }
        }
#pragma unroll
        for (int d = 1; d <= 2; d <<= 1) {
            float om1 = __shfl_xor(m1, d);
            int   oi1 = __shfl_xor(i1, d);
            float om2 = __shfl_xor(m2, d);
            int   oi2 = __shfl_xor(i2, d);
            bool agt = (m1 > om1) || (m1 == om1 && i1 < oi1);
            float a1 = agt ? m1 : om1;  int ai1 = agt ? i1 : oi1;
            float c2 = agt ? m2 : om2;  int ci2 = agt ? i2 : oi2;
            float c1 = agt ? om1 : m1;  int ci1 = agt ? oi1 : i1;
            bool sgt = (c2 > c1) || (c2 == c1 && ci2 < ci1);
            m1 = a1; i1 = ai1;
            m2 = sgt ? c2 : c1; i2 = sgt ? ci2 : ci1;
        }
        if (q == 0) {
            float e2  = expf(m2 - m1);
            float inv = 1.f / (1.f + e2);
            int t = t0 + tt;
            out_nv[t * 2 + 0]  = inv;
            out_nv[t * 2 + 1]  = e2 * inv;
            out_idx[t * 2 + 0] = (float)i1;
            out_idx[t * 2 + 1] = (float)i2;
        }
    }
}

extern "C" void kernel_launch(void* const* d_in, const int* in_sizes, int n_in,
                              void* d_out, int out_size, void* d_ws, size_t ws_size,
                              hipStream_t stream) {
    const float* X = (const float*)d_in[0];
    const float* W = (const float*)d_in[1];
    const float* B = (const float*)d_in[2];
    float* out = (float*)d_out;

    unsigned short* WH = (unsigned short*)d_ws;          // 256 KB
    unsigned short* WL = WH + (size_t)DIM * NE;          // +256 KB

    hipLaunchKernelGGL(pack_w, dim3((DIM * NE + 255) / 256), dim3(256), 0, stream, W, WH, WL);
    hipLaunchKernelGGL(router_mfma, dim3(NTOK / TPB), dim3(512), 0, stream, X, WH, WL, B, out);
}

// Round 14
// 36.457 us; speedup vs baseline: 1.3736x; 1.0055x over previous
//
#include <hip/hip_runtime.h>
#include <hip/hip_bf16.h>

#define NTOK 16384
#define DIM  2048
#define NE   64
#define TPB  64                // tokens per block = 4 tiles
#define NTILE 4
#define KG   8                 // wave = k-group
#define KPW  (DIM / KG)        // 256 k per wave
#define KSTEPS (KPW / 32)      // 8 mfma k-steps per wave
#define NKS_ALL (DIM / 32)     // 64 total k-steps
#define LP   65

typedef __attribute__((ext_vector_type(8))) short  short8;   // 8 bf16 (4 VGPRs)
typedef __attribute__((ext_vector_type(4))) float  f32x4;

static __device__ __forceinline__ unsigned short f2bf(float f) {
    unsigned u = __float_as_uint(f);
    unsigned r = (u + 0x7fffu + ((u >> 16) & 1u)) >> 16;   // RNE
    return (unsigned short)r;
}
static __device__ __forceinline__ float bf2f(unsigned short h) {
    return __uint_as_float(((unsigned)h) << 16);
}

// packed split: (x0,x1) -> hi word [bf(x1)|bf(x0)], lo word [bf(r1)|bf(r0)]
static __device__ __forceinline__ void cvt_pair(float x0, float x1,
                                                unsigned& hi, unsigned& lo) {
    union { __hip_bfloat162 b; unsigned u; } h, l;
    h.b = __float22bfloat162_rn(float2{x0, x1});           // v_cvt_pk_bf16_f32
    float h0 = __uint_as_float(h.u << 16);
    float h1 = __uint_as_float(h.u & 0xffff0000u);
    l.b = __float22bfloat162_rn(float2{x0 - h0, x1 - h1});
    hi = h.u; lo = l.u;
}

// ---- prologue: split W into hi/lo bf16, packed in MFMA B-fragment order ----
// vectorized: 4 consecutive experts (same k) per thread; frag-row never crossed
__global__ void pack_w(const float* __restrict__ W,
                       unsigned short* __restrict__ WH,
                       unsigned short* __restrict__ WL) {
    int idx = (blockIdx.x * 256 + threadIdx.x) * 4;
    if (idx >= DIM * NE) return;
    int k = idx / NE, e = idx % NE;          // e in {0,4,...,60}
    float4 w4 = *(const float4*)(W + idx);
    int etile = e >> 4, col = e & 15;        // col <= 12: all 4 in same etile
    int kstep = k >> 5, lsub = (k >> 3) & 3, j = k & 7;
    size_t off = (((size_t)etile * NKS_ALL + kstep) * 64 + (lsub * 16 + col)) * 8 + j;
    float w[4] = {w4.x, w4.y, w4.z, w4.w};
#pragma unroll
    for (int i = 0; i < 4; ++i) {
        unsigned short h = f2bf(w[i]);
        WH[off + i * 8] = h;
        WL[off + i * 8] = f2bf(w[i] - bf2f(h));
    }
}

// ---- main: 3-pass split-bf16 MFMA; 8 waves, NTILE=4, depth-3 X prefetch ----
__global__ __launch_bounds__(512, 2) void router_mfma(
    const float* __restrict__ X,
    const unsigned short* __restrict__ WH,
    const unsigned short* __restrict__ WL,
    const float* __restrict__ B, float* __restrict__ out)
{
    __shared__ float red[KG][TPB][LP];   // 133 KB k-partials (lg folded into red[0])

    const int tid  = threadIdx.x;
    const int lane = tid & 63;
    const int kg   = __builtin_amdgcn_readfirstlane(tid >> 6);  // wave = k group 0..7
    const int t0   = blockIdx.x * TPB;

    const int arow = lane & 15;          // A row within 16-tile
    const int koff = (lane >> 4) * 8;    // k offset within 32-step

    const float* xp0 = X + (size_t)(t0 +  0 + arow) * DIM + kg * KPW + koff;
    const float* xp1 = X + (size_t)(t0 + 16 + arow) * DIM + kg * KPW + koff;
    const float* xp2 = X + (size_t)(t0 + 32 + arow) * DIM + kg * KPW + koff;
    const float* xp3 = X + (size_t)(t0 + 48 + arow) * DIM + kg * KPW + koff;

    const int ksbase = kg * KSTEPS;

    f32x4 acc[NTILE][4];
#pragma unroll
    for (int t = 0; t < NTILE; ++t)
#pragma unroll
        for (int et = 0; et < 4; ++et) acc[t][et] = (f32x4){0.f, 0.f, 0.f, 0.f};

    float4 xA[NTILE][2], xB[NTILE][2], xC[NTILE][2];
    short8 bhA[4], blA[4], bhB[4], blB[4];

#define LOADX(buf, s) do {                                                    \
    buf[0][0] = *(const float4*)(xp0 + (s) * 32);                             \
    buf[0][1] = *(const float4*)(xp0 + (s) * 32 + 4);                         \
    buf[1][0] = *(const float4*)(xp1 + (s) * 32);                             \
    buf[1][1] = *(const float4*)(xp1 + (s) * 32 + 4);                         \
    buf[2][0] = *(const float4*)(xp2 + (s) * 32);                             \
    buf[2][1] = *(const float4*)(xp2 + (s) * 32 + 4);                         \
    buf[3][0] = *(const float4*)(xp3 + (s) * 32);                             \
    buf[3][1] = *(const float4*)(xp3 + (s) * 32 + 4);                         \
  } while (0)

#define LOADB(bh_, bl_, s) do {                                               \
    _Pragma("unroll")                                                         \
    for (int et = 0; et < 4; ++et) {                                          \
        size_t foff = (((size_t)et * NKS_ALL + ksbase + (s)) * 64 + lane) * 8;\
        bh_[et] = *(const short8*)(WH + foff);                                \
        bl_[et] = *(const short8*)(WL + foff);                                \
    }                                                                         \
  } while (0)

#define COMPUTE(xv, bh_, bl_) do {                                            \
    _Pragma("unroll")                                                         \
    for (int t = 0; t < NTILE; ++t) {                                         \
        union { unsigned u[4]; short8 s8; } ah, al;                           \
        cvt_pair(xv[t][0].x, xv[t][0].y, ah.u[0], al.u[0]);                   \
        cvt_pair(xv[t][0].z, xv[t][0].w, ah.u[1], al.u[1]);                   \
        cvt_pair(xv[t][1].x, xv[t][1].y, ah.u[2], al.u[2]);                   \
        cvt_pair(xv[t][1].z, xv[t][1].w, ah.u[3], al.u[3]);                   \
        _Pragma("unroll")                                                     \
        for (int et = 0; et < 4; ++et) {                                      \
            acc[t][et] = __builtin_amdgcn_mfma_f32_16x16x32_bf16(ah.s8, bh_[et], acc[t][et], 0, 0, 0); \
            acc[t][et] = __builtin_amdgcn_mfma_f32_16x16x32_bf16(ah.s8, bl_[et], acc[t][et], 0, 0, 0); \
            acc[t][et] = __builtin_amdgcn_mfma_f32_16x16x32_bf16(al.s8, bh_[et], acc[t][et], 0, 0, 0); \
        }                                                                     \
    }                                                                         \
  } while (0)

    // prologue: X 3 steps deep, B 2 steps deep
    LOADX(xA, 0); LOADB(bhA, blA, 0);
    LOADX(xB, 1); LOADB(bhB, blB, 1);
    LOADX(xC, 2);

    // steady state: compute(s), then B(s+2) (needed sooner) before X(s+3)
    COMPUTE(xA, bhA, blA); LOADB(bhA, blA, 2); LOADX(xA, 3);
    COMPUTE(xB, bhB, blB); LOADB(bhB, blB, 3); LOADX(xB, 4);
    COMPUTE(xC, bhA, blA); LOADB(bhA, blA, 4); LOADX(xC, 5);
    COMPUTE(xA, bhB, blB); LOADB(bhB, blB, 5); LOADX(xA, 6);
    COMPUTE(xB, bhA, blA); LOADB(bhA, blA, 6); LOADX(xB, 7);
    COMPUTE(xC, bhB, blB); LOADB(bhB, blB, 7);
    COMPUTE(xA, bhA, blA);
    COMPUTE(xB, bhB, blB);

    // C frag: col = lane&15, row = (lane>>4)*4 + r
#pragma unroll
    for (int t = 0; t < NTILE; ++t)
#pragma unroll
        for (int et = 0; et < 4; ++et)
#pragma unroll
            for (int r = 0; r < 4; ++r)
                red[kg][t * 16 + (lane >> 4) * 4 + r][et * 16 + (lane & 15)] = acc[t][et][r];
    __syncthreads();

    float* out_nv  = out + (size_t)NTOK * NE;
    float* out_idx = out_nv + (size_t)NTOK * 2;

    // ---- reduce over KG, add bias, store logits; winners back into red[0] ----
#pragma unroll
    for (int k = 0; k < 2; ++k) {
        const int idx = tid + k * 512;    // 1024 items: 64 tok x 16 col-quads
        const int rt = idx >> 4;
        const int re = (idx & 15) * 4;
        float4 s = {0.f, 0.f, 0.f, 0.f};
#pragma unroll
        for (int g = 0; g < KG; ++g) {
            s.x += red[g][rt][re + 0];
            s.y += red[g][rt][re + 1];
            s.z += red[g][rt][re + 2];
            s.w += red[g][rt][re + 3];
        }
        float4 bb = *(const float4*)(B + re);
        s.x += bb.x; s.y += bb.y; s.z += bb.z; s.w += bb.w;
        *(float4*)&out[(size_t)(t0 + rt) * NE + re] = s;
        red[0][rt][re + 0] = s.x;     // each slot owned by exactly this thread
        red[0][rt][re + 1] = s.y;
        red[0][rt][re + 2] = s.z;
        red[0][rt][re + 3] = s.w;
    }
    __syncthreads();

    // ---- top-2 + renormalize: 4 lanes/token, shfl-merge (lowest-index ties) ----
    if (tid < 4 * TPB) {
        const int tt = tid >> 2;         // token 0..63
        const int q  = tid & 3;          // expert quarter
        float m1 = -1e30f, m2 = -1e30f;
        int   i1 = 0, i2 = 0;
#pragma unroll
        for (int j = 0; j < 16; ++j) {
            int   e = q * 16 + j;
            float v = red[0][tt][e];
            if (v > m1)      { m2 = m1; i2 = i1; m1 = v; i1 = e; }
            else if (v > m2) { m2 = v;  i2 = e; }
        }
#pragma unroll
        for (int d = 1; d <= 2; d <<= 1) {
            float om1 = __shfl_xor(m1, d);
            int   oi1 = __shfl_xor(i1, d);
            float om2 = __shfl_xor(m2, d);
            int   oi2 = __shfl_xor(i2, d);
            bool agt = (m1 > om1) || (m1 == om1 && i1 < oi1);
            float a1 = agt ? m1 : om1;  int ai1 = agt ? i1 : oi1;
            float c2 = agt ? m2 : om2;  int ci2 = agt ? i2 : oi2;
            float c1 = agt ? om1 : m1;  int ci1 = agt ? oi1 : i1;
            bool sgt = (c2 > c1) || (c2 == c1 && ci2 < ci1);
            m1 = a1; i1 = ai1;
            m2 = sgt ? c2 : c1; i2 = sgt ? ci2 : ci1;
        }
        if (q == 0) {
            float e2  = __expf(m2 - m1);
            float inv = 1.f / (1.f + e2);
            int t = t0 + tt;
            out_nv[t * 2 + 0]  = inv;
            out_nv[t * 2 + 1]  = e2 * inv;
            out_idx[t * 2 + 0] = (float)i1;
            out_idx[t * 2 + 1] = (float)i2;
        }
    }
}

extern "C" void kernel_launch(void* const* d_in, const int* in_sizes, int n_in,
                              void* d_out, int out_size, void* d_ws, size_t ws_size,
                              hipStream_t stream) {
    const float* X = (const float*)d_in[0];
    const float* W = (const float*)d_in[1];
    const float* B = (const float*)d_in[2];
    float* out = (float*)d_out;

    unsigned short* WH = (unsigned short*)d_ws;          // 256 KB
    unsigned short* WL = WH + (size_t)DIM * NE;          // +256 KB

    hipLaunchKernelGGL(pack_w, dim3(DIM * NE / 1024), dim3(256), 0, stream, W, WH, WL);
    hipLaunchKernelGGL(router_mfma, dim3(NTOK / TPB), dim3(512), 0, stream, X, WH, WL, B, out);
}